// Round 5
// baseline (856.299 us; speedup 1.0000x reference)
//
#include <hip/hip_runtime.h>
#include <hip/hip_bf16.h>
#include <stdint.h>

#define L 1024
#define D 1024
#define NLAYER 4
#define NSTATE 16
#define DI 2048
#define DTR 64
#define KCONV 4
#define XD 96      // DTR + 2*NSTATE
#define NC 64      // scan chunks
#define CT 16      // timesteps per chunk (L/NC)
#define KSPLIT 8   // x_proj split-K
#define BK 32

typedef __attribute__((ext_vector_type(8))) short short8;
typedef __attribute__((ext_vector_type(4))) float floatx4;

__device__ __forceinline__ float siluf(float x) { return x / (1.f + __expf(-x)); }

__device__ __forceinline__ unsigned short f2bf(float x) {
    __hip_bfloat16 b = __float2bfloat16(x);
    return *reinterpret_cast<unsigned short*>(&b);
}

__device__ __forceinline__ short8 pack8(floatx4 a, floatx4 b) {
    short8 o;
    o[0] = (short)f2bf(a.x); o[1] = (short)f2bf(a.y);
    o[2] = (short)f2bf(a.z); o[3] = (short)f2bf(a.w);
    o[4] = (short)f2bf(b.x); o[5] = (short)f2bf(b.y);
    o[6] = (short)f2bf(b.z); o[7] = (short)f2bf(b.w);
    return o;
}

#ifndef __has_builtin
#define __has_builtin(x) 0
#endif
#if __has_builtin(__builtin_amdgcn_global_load_lds)
#define HAVE_GLD 1
#define GLD(gp, lp) __builtin_amdgcn_global_load_lds(                                  \
    (const __attribute__((address_space(1))) void*)(gp),                               \
    (__attribute__((address_space(3))) void*)(lp), 16, 0, 0)
#endif

// ---------------- MFMA GEMM, double-buffered, inline fp32->bf16 B staging ----------------
// C[M,N] = A[M,K]*B[N,K]^T.  Tile 128(M) x 64(N) x 32(K), 4 waves 2x2.
// ASRC: 0 = A is bf16 (GLD direct-to-LDS); 1 = A is fp32, track row sum(x^2), scale epilogue
//       by rsqrt(mean+eps)  [fused RMSNorm]; 2 = A = sum of KSPLIT fp32 partials (stride pstride).
// B always fp32, converted to bf16 during staging; BNW: multiply B element by nw[k] (norm_w fold).
// EPI: 0 plain; 1 softplus(c+bias[n]); 2 c+resid[m*ldc+n]
template <int EPI, int ASRC, bool BNW>
__global__ __launch_bounds__(256, 2) void gemm_mfma(
    const void* __restrict__ Ax, int lda,
    const float* __restrict__ Bw, int ldb, int Brows,
    float* __restrict__ C, int ldc, int Nvalid,
    int kchunk, long zstride,
    const float* __restrict__ bias, const float* __restrict__ resid,
    const float* __restrict__ nw, long pstride) {
    __shared__ __align__(16) __hip_bfloat16 As[2][128 * BK];
    __shared__ __align__(16) __hip_bfloat16 Bs[2][64 * BK];
    __shared__ float normS[128];
    int tid = threadIdx.x;
    int wave = tid >> 6, lane = tid & 63;
    int m0 = blockIdx.y * 128, n0 = blockIdx.x * 64;
    int k_lo = blockIdx.z * kchunk, k_hi = k_lo + kchunk;
    C += (long)blockIdx.z * zstride;
    int wr = wave >> 1, wc = wave & 1;
    int srow = lane >> 2, scol = (lane & 3) * 8;
    int q = lane >> 4, r = lane & 15;

    floatx4 acc[4][2] = {};

    const __hip_bfloat16* gA0b = nullptr;
    const __hip_bfloat16* gA1b = nullptr;
    const float* gA0f = nullptr;
    const float* gA1f = nullptr;
    if (ASRC == 0) {
        gA0b = (const __hip_bfloat16*)Ax + (long)(m0 + wave * 32 + srow) * lda + scol;
        gA1b = gA0b + (long)16 * lda;
    } else {
        gA0f = (const float*)Ax + (long)(m0 + wave * 32 + srow) * lda + scol;
        gA1f = gA0f + (long)16 * lda;
    }
    int brow = n0 + wave * 16 + srow;
    const float* gB = Bw + (long)brow * ldb + scol;
    bool bok = brow < Brows;

    float ss0 = 0.f, ss1 = 0.f;

    auto stage = [&](int k0, int p) {
        // ---- A tile ----
        if (ASRC == 0) {
#ifdef HAVE_GLD
            GLD(gA0b + k0, &As[p][(wave * 32) * BK]);
            GLD(gA1b + k0, &As[p][(wave * 32 + 16) * BK]);
#else
            *(short8*)(&As[p][(wave * 32 + srow) * BK + scol]) = *(const short8*)(gA0b + k0);
            *(short8*)(&As[p][(wave * 32 + 16 + srow) * BK + scol]) = *(const short8*)(gA1b + k0);
#endif
        } else if (ASRC == 1) {
            floatx4 v0 = *(const floatx4*)(gA0f + k0);
            floatx4 v1 = *(const floatx4*)(gA0f + k0 + 4);
            floatx4 w0 = *(const floatx4*)(gA1f + k0);
            floatx4 w1 = *(const floatx4*)(gA1f + k0 + 4);
            ss0 += v0.x * v0.x + v0.y * v0.y + v0.z * v0.z + v0.w * v0.w
                 + v1.x * v1.x + v1.y * v1.y + v1.z * v1.z + v1.w * v1.w;
            ss1 += w0.x * w0.x + w0.y * w0.y + w0.z * w0.z + w0.w * w0.w
                 + w1.x * w1.x + w1.y * w1.y + w1.z * w1.z + w1.w * w1.w;
            *(short8*)(&As[p][(wave * 32 + srow) * BK + scol]) = pack8(v0, v1);
            *(short8*)(&As[p][(wave * 32 + 16 + srow) * BK + scol]) = pack8(w0, w1);
        } else {  // ASRC == 2: sum KSPLIT fp32 partials
            floatx4 v0 = {0.f, 0.f, 0.f, 0.f}, v1 = v0, w0 = v0, w1 = v0;
#pragma unroll
            for (int sp = 0; sp < KSPLIT; ++sp) {
                const float* p0 = gA0f + sp * pstride + k0;
                const float* p1 = gA1f + sp * pstride + k0;
                v0 += *(const floatx4*)(p0);
                v1 += *(const floatx4*)(p0 + 4);
                w0 += *(const floatx4*)(p1);
                w1 += *(const floatx4*)(p1 + 4);
            }
            *(short8*)(&As[p][(wave * 32 + srow) * BK + scol]) = pack8(v0, v1);
            *(short8*)(&As[p][(wave * 32 + 16 + srow) * BK + scol]) = pack8(w0, w1);
        }
        // ---- B tile (fp32 -> bf16 inline) ----
        floatx4 b0 = {0.f, 0.f, 0.f, 0.f}, b1 = b0;
        if (bok) {
            b0 = *(const floatx4*)(gB + k0);
            b1 = *(const floatx4*)(gB + k0 + 4);
        }
        if (BNW) {
            b0 *= *(const floatx4*)(nw + k0 + scol);
            b1 *= *(const floatx4*)(nw + k0 + scol + 4);
        }
        *(short8*)(&Bs[p][(wave * 16 + srow) * BK + scol]) = pack8(b0, b1);
    };

    stage(k_lo, 0);
    int p = 0;
    for (int k0 = k_lo; k0 < k_hi; k0 += BK) {
        __syncthreads();
        if (k0 + BK < k_hi) stage(k0 + BK, p ^ 1);
        const short* Ap = (const short*)As[p];
        const short* Bp = (const short*)Bs[p];
        short8 af[4], bfr[2];
#pragma unroll
        for (int i = 0; i < 4; ++i)
            af[i] = *(const short8*)(Ap + (wr * 64 + i * 16 + r) * BK + q * 8);
#pragma unroll
        for (int j = 0; j < 2; ++j)
            bfr[j] = *(const short8*)(Bp + (wc * 32 + j * 16 + r) * BK + q * 8);
#pragma unroll
        for (int i = 0; i < 4; ++i)
#pragma unroll
            for (int j = 0; j < 2; ++j)
                acc[i][j] = __builtin_amdgcn_mfma_f32_16x16x32_bf16(af[i], bfr[j], acc[i][j], 0, 0, 0);
        p ^= 1;
    }

    if (ASRC == 1) {  // finish fused RMSNorm: reduce row sums across the 4-lane quads
        ss0 += __shfl_xor(ss0, 1); ss0 += __shfl_xor(ss0, 2);
        ss1 += __shfl_xor(ss1, 1); ss1 += __shfl_xor(ss1, 2);
        if ((lane & 3) == 0) {
            normS[wave * 32 + srow] = ss0;
            normS[wave * 32 + 16 + srow] = ss1;
        }
        __syncthreads();
    }

#pragma unroll
    for (int i = 0; i < 4; ++i) {
        int lr0 = wr * 64 + i * 16 + q * 4;
#pragma unroll
        for (int j = 0; j < 2; ++j) {
            int ncol = n0 + wc * 32 + j * 16 + r;
            if (ncol < Nvalid) {
#pragma unroll
                for (int rr = 0; rr < 4; ++rr) {
                    float v = acc[i][j][rr];
                    int lr = lr0 + rr;
                    int m = m0 + lr;
                    if (ASRC == 1)
                        v *= rsqrtf(normS[lr] * (1.f / 1024.f) + 1e-5f);
                    if (EPI == 1) {
                        v += bias[ncol];
                        v = v > 20.f ? v : log1pf(__expf(v));
                    } else if (EPI == 2) {
                        v += resid[(long)m * ldc + ncol];
                    }
                    C[(long)m * ldc + ncol] = v;
                }
            }
        }
    }
}

// ---------------- causal depthwise conv + bias + SiLU -> bf16 ----------------
__global__ __launch_bounds__(256) void conv_silu_kernel(const float* __restrict__ xz,
                                                        const float* __restrict__ cw,
                                                        const float* __restrict__ cb,
                                                        __hip_bfloat16* __restrict__ u) {
    int idx = blockIdx.x * 256 + threadIdx.x;  // t*DI + d
    int d = idx & (DI - 1);
    int t = idx >> 11;
    float acc = cb[d];
#pragma unroll
    for (int k = 0; k < KCONV; ++k) {
        int tk = t - (KCONV - 1) + k;
        if (tk >= 0) acc += xz[(size_t)tk * (2 * DI) + d] * cw[d * KCONV + k];
    }
    u[idx] = __float2bfloat16(siluf(acc));
}

// ---------------- selective scan: phase A (per-chunk aggregates) ----------------
// B-columns staged from split-K partial sums (xdbl never materialized)
__global__ __launch_bounds__(256) void scanA_kernel(const float* __restrict__ delta,
                                                    const __hip_bfloat16* __restrict__ u,
                                                    const float* __restrict__ part,
                                                    const float* __restrict__ Alog,
                                                    float* __restrict__ Ach,
                                                    float* __restrict__ Bch) {
    int d = blockIdx.x * 256 + threadIdx.x;
    int c = blockIdx.y;
    __shared__ __align__(16) float Bsh[CT * NSTATE];
    int tt0 = threadIdx.x >> 4, c0 = threadIdx.x & 15;
    {
        float s = 0.f;
        size_t base = (size_t)(c * CT + tt0) * XD + DTR + c0;
#pragma unroll
        for (int sp = 0; sp < KSPLIT; ++sp) s += part[(size_t)sp * L * XD + base];
        Bsh[threadIdx.x] = s;
    }
    __syncthreads();

    float aval[NSTATE];
    const float4* Al4 = (const float4*)(Alog + (size_t)d * NSTATE);
#pragma unroll
    for (int n4 = 0; n4 < 4; ++n4) {
        float4 t = Al4[n4];
        aval[n4 * 4 + 0] = -__expf(t.x);
        aval[n4 * 4 + 1] = -__expf(t.y);
        aval[n4 * 4 + 2] = -__expf(t.z);
        aval[n4 * 4 + 3] = -__expf(t.w);
    }
    float h[NSTATE], ap[NSTATE];
#pragma unroll
    for (int n = 0; n < NSTATE; ++n) { h[n] = 0.f; ap[n] = 1.f; }

    for (int tt = 0; tt < CT; ++tt) {
        int t = c * CT + tt;
        float dl = delta[(size_t)t * DI + d];
        float uu = __bfloat162float(u[(size_t)t * DI + d]);
        float du = dl * uu;
        const float4* Bv = (const float4*)(Bsh + tt * NSTATE);
#pragma unroll
        for (int n4 = 0; n4 < 4; ++n4) {
            float4 b = Bv[n4];
            float bb[4] = {b.x, b.y, b.z, b.w};
#pragma unroll
            for (int k = 0; k < 4; ++k) {
                int n = n4 * 4 + k;
                float a = __expf(dl * aval[n]);
                h[n] = a * h[n] + du * bb[k];
                ap[n] *= a;
            }
        }
    }
    float4* Ao = (float4*)(Ach + ((size_t)c * DI + d) * NSTATE);
    float4* Bo = (float4*)(Bch + ((size_t)c * DI + d) * NSTATE);
#pragma unroll
    for (int n4 = 0; n4 < 4; ++n4) {
        Ao[n4] = make_float4(ap[n4 * 4], ap[n4 * 4 + 1], ap[n4 * 4 + 2], ap[n4 * 4 + 3]);
        Bo[n4] = make_float4(h[n4 * 4], h[n4 * 4 + 1], h[n4 * 4 + 2], h[n4 * 4 + 3]);
    }
}

// ---------------- scan phase B: sequential chunk combine; Hinit overwrites Ach ----------------
__global__ __launch_bounds__(256) void scanB_kernel(float* __restrict__ Ach,
                                                    const float* __restrict__ Bch) {
    long i = blockIdx.x * 256 + threadIdx.x;  // < DI*NSTATE
    const long S = (long)DI * NSTATE;
    float h = 0.f;
    for (int c = 0; c < NC; ++c) {
        float a = Ach[c * S + i];
        float b = Bch[c * S + i];
        Ach[c * S + i] = h;  // becomes Hinit
        h = a * h + b;
    }
}

// ---------------- scan phase C: replay with init state, fused gate -> yg bf16 ----------------
__global__ __launch_bounds__(256) void scanC_kernel(const float* __restrict__ delta,
                                                    const __hip_bfloat16* __restrict__ u,
                                                    const float* __restrict__ part,
                                                    const float* __restrict__ Alog,
                                                    const float* __restrict__ Hin,
                                                    const float* __restrict__ xz,
                                                    const float* __restrict__ Dskip,
                                                    __hip_bfloat16* __restrict__ yg) {
    int d = blockIdx.x * 256 + threadIdx.x;
    int c = blockIdx.y;
    __shared__ __align__(16) float Bsh[CT * NSTATE];
    __shared__ __align__(16) float Csh[CT * NSTATE];
    int tt0 = threadIdx.x >> 4, c0 = threadIdx.x & 15;
    {
        float sb = 0.f, sc = 0.f;
        size_t base = (size_t)(c * CT + tt0) * XD + DTR + c0;
#pragma unroll
        for (int sp = 0; sp < KSPLIT; ++sp) {
            sb += part[(size_t)sp * L * XD + base];
            sc += part[(size_t)sp * L * XD + base + NSTATE];
        }
        Bsh[threadIdx.x] = sb;
        Csh[threadIdx.x] = sc;
    }
    __syncthreads();

    float aval[NSTATE];
    const float4* Al4 = (const float4*)(Alog + (size_t)d * NSTATE);
#pragma unroll
    for (int n4 = 0; n4 < 4; ++n4) {
        float4 t = Al4[n4];
        aval[n4 * 4 + 0] = -__expf(t.x);
        aval[n4 * 4 + 1] = -__expf(t.y);
        aval[n4 * 4 + 2] = -__expf(t.z);
        aval[n4 * 4 + 3] = -__expf(t.w);
    }
    float h[NSTATE];
    const float4* Hi = (const float4*)(Hin + ((size_t)c * DI + d) * NSTATE);
#pragma unroll
    for (int n4 = 0; n4 < 4; ++n4) {
        float4 t = Hi[n4];
        h[n4 * 4 + 0] = t.x; h[n4 * 4 + 1] = t.y; h[n4 * 4 + 2] = t.z; h[n4 * 4 + 3] = t.w;
    }
    float dsk = Dskip[d];

    for (int tt = 0; tt < CT; ++tt) {
        int t = c * CT + tt;
        float dl = delta[(size_t)t * DI + d];
        float uu = __bfloat162float(u[(size_t)t * DI + d]);
        float du = dl * uu;
        const float4* Bv = (const float4*)(Bsh + tt * NSTATE);
        const float4* Cv = (const float4*)(Csh + tt * NSTATE);
        float y = 0.f;
#pragma unroll
        for (int n4 = 0; n4 < 4; ++n4) {
            float4 b = Bv[n4];
            float4 cc = Cv[n4];
            float bb[4] = {b.x, b.y, b.z, b.w};
            float cv[4] = {cc.x, cc.y, cc.z, cc.w};
#pragma unroll
            for (int k = 0; k < 4; ++k) {
                int n = n4 * 4 + k;
                float a = __expf(dl * aval[n]);
                h[n] = a * h[n] + du * bb[k];
                y += h[n] * cv[k];
            }
        }
        float z = xz[(size_t)t * (2 * DI) + DI + d];
        yg[(size_t)t * DI + d] = __float2bfloat16((y + uu * dsk) * siluf(z));
    }
}

// ---------------- host orchestration ----------------
extern "C" void kernel_launch(void* const* d_in, const int* in_sizes, int n_in,
                              void* d_out, int out_size, void* d_ws, size_t ws_size,
                              hipStream_t stream) {
    const float* x      = (const float*)d_in[0];
    const float* norm_w = (const float*)d_in[1];
    const float* in_w   = (const float*)d_in[2];
    const float* conv_w = (const float*)d_in[3];
    const float* conv_b = (const float*)d_in[4];
    const float* xproj_w= (const float*)d_in[5];
    const float* dt_w   = (const float*)d_in[6];
    const float* dt_b   = (const float*)d_in[7];
    const float* A_log  = (const float*)d_in[8];
    const float* D_skip = (const float*)d_in[9];
    const float* out_w  = (const float*)d_in[10];
    float* out = (float*)d_out;

    uint8_t* wp = (uint8_t*)d_ws;
    auto alloc = [&](size_t bytes) {
        uint8_t* p = wp;
        wp += (bytes + 255) & ~(size_t)255;
        return p;
    };
    float*          xz    = (float*)alloc((size_t)L * 2 * DI * 4);
    __hip_bfloat16* u_bf  = (__hip_bfloat16*)alloc((size_t)L * DI * 2);
    float*          part  = (float*)alloc((size_t)KSPLIT * L * XD * 4);
    float*          delta = (float*)alloc((size_t)L * DI * 4);
    __hip_bfloat16* yg_bf = (__hip_bfloat16*)alloc((size_t)L * DI * 2);
    float*          Ach   = (float*)alloc((size_t)NC * DI * NSTATE * 4);  // Hinit aliases this
    float*          Bch   = (float*)alloc((size_t)NC * DI * NSTATE * 4);

    for (int l = 0; l < NLAYER; ++l) {
        const float* xin = (l == 0) ? x : out;

        // in_proj (+fused RMSNorm): [1024,1024]x[4096,1024]^T -> xz fp32
        gemm_mfma<0, 1, true><<<dim3(4096 / 64, L / 128, 1), 256, 0, stream>>>(
            xin, D, in_w + (size_t)l * 4096 * 1024, D, 4096,
            xz, 4096, 4096, D, 0, nullptr, nullptr, norm_w + (size_t)l * D, 0);

        conv_silu_kernel<<<L * DI / 256, 256, 0, stream>>>(
            xz, conv_w + (size_t)l * DI * KCONV, conv_b + (size_t)l * DI, u_bf);

        // x_proj split-K: [1024,2048]x[96,2048]^T -> part[s][1024][96]
        gemm_mfma<0, 0, false><<<dim3(2, L / 128, KSPLIT), 256, 0, stream>>>(
            u_bf, DI, xproj_w + (size_t)l * 96 * 2048, DI, 96,
            part, XD, XD, DI / KSPLIT, (long)L * XD, nullptr, nullptr, nullptr, 0);

        // dt_proj (+fused partial reduce): A = sum_s part[s], [1024,64]x[2048,64]^T -> delta
        gemm_mfma<1, 2, false><<<dim3(2048 / 64, L / 128, 1), 256, 0, stream>>>(
            part, XD, dt_w + (size_t)l * 2048 * 64, DTR, 2048,
            delta, DI, DI, DTR, 0, dt_b + (size_t)l * DI, nullptr, nullptr, (long)L * XD);

        scanA_kernel<<<dim3(DI / 256, NC), 256, 0, stream>>>(
            delta, u_bf, part, A_log + (size_t)l * DI * NSTATE, Ach, Bch);
        scanB_kernel<<<(DI * NSTATE) / 256, 256, 0, stream>>>(Ach, Bch);
        scanC_kernel<<<dim3(DI / 256, NC), 256, 0, stream>>>(
            delta, u_bf, part, A_log + (size_t)l * DI * NSTATE, Ach, xz,
            D_skip + (size_t)l * DI, yg_bf);

        // out_proj: [1024,2048]x[1024,2048]^T + resid -> out
        gemm_mfma<2, 0, false><<<dim3(1024 / 64, L / 128, 1), 256, 0, stream>>>(
            yg_bf, DI, out_w + (size_t)l * 1024 * 2048, DI, 1024,
            out, D, D, DI, 0, nullptr, xin, nullptr, 0);
    }
}

// Round 6
// 638.123 us; speedup vs baseline: 1.3419x; 1.3419x over previous
//
#include <hip/hip_runtime.h>
#include <hip/hip_bf16.h>
#include <stdint.h>

#define L 1024
#define D 1024
#define NLAYER 4
#define NSTATE 16
#define DI 2048
#define DTR 64
#define KCONV 4
#define XD 96      // DTR + 2*NSTATE
#define NC 64      // scan chunks
#define CT 16      // timesteps per chunk (L/NC)
#define KSPLIT 8   // x_proj split-K
#define BK 32

typedef __attribute__((ext_vector_type(8))) short short8;
typedef __attribute__((ext_vector_type(4))) float floatx4;

__device__ __forceinline__ float siluf(float x) { return x / (1.f + __expf(-x)); }

__device__ __forceinline__ unsigned short f2bf(float x) {
    __hip_bfloat16 b = __float2bfloat16(x);
    return *reinterpret_cast<unsigned short*>(&b);
}

__device__ __forceinline__ short8 pack8(floatx4 a, floatx4 b) {
    short8 o;
    o[0] = (short)f2bf(a.x); o[1] = (short)f2bf(a.y);
    o[2] = (short)f2bf(a.z); o[3] = (short)f2bf(a.w);
    o[4] = (short)f2bf(b.x); o[5] = (short)f2bf(b.y);
    o[6] = (short)f2bf(b.z); o[7] = (short)f2bf(b.w);
    return o;
}

#ifndef __has_builtin
#define __has_builtin(x) 0
#endif
#if __has_builtin(__builtin_amdgcn_global_load_lds)
#define HAVE_GLD 1
#define GLD(gp, lp) __builtin_amdgcn_global_load_lds(                                  \
    (const __attribute__((address_space(1))) void*)(gp),                               \
    (__attribute__((address_space(3))) void*)(lp), 16, 0, 0)
#endif

// ---------------- all-layer weight fp32->bf16 conversion (1 launch, 64B/thread) ----------------
#define N_IN4  1048576   // 4096*1024/4
#define N_XP4  49152     // 96*2048/4
#define N_DT4  32768     // 2048*64/4
#define N_OUT4 524288    // 1024*2048/4
#define N_CVT4 (N_IN4 + N_XP4 + N_DT4 + N_OUT4)
#define CVT_THREADS (NLAYER * N_CVT4 / 4)

__global__ __launch_bounds__(256) void cvt_all_kernel(
    const float* __restrict__ in_w, const float* __restrict__ xp_w,
    const float* __restrict__ dt_w, const float* __restrict__ out_w,
    __hip_bfloat16* __restrict__ in_bf, __hip_bfloat16* __restrict__ xp_bf,
    __hip_bfloat16* __restrict__ dt_bf, __hip_bfloat16* __restrict__ out_bf) {
    int gi = blockIdx.x * 256 + threadIdx.x;
    if (gi >= CVT_THREADS) return;
    int layer = gi / (N_CVT4 / 4);
    int i = (gi - layer * (N_CVT4 / 4)) * 4;
    const float* src;
    __hip_bfloat16* dst;
    int off;
    if (i < N_IN4) {
        src = in_w + (size_t)layer * 4096 * 1024;
        dst = in_bf + (size_t)layer * 4096 * 1024; off = i;
    } else if (i < N_IN4 + N_XP4) {
        src = xp_w + (size_t)layer * 96 * 2048;
        dst = xp_bf + (size_t)layer * 128 * 2048; off = i - N_IN4;  // rows 96..127 stay poison (finite)
    } else if (i < N_IN4 + N_XP4 + N_DT4) {
        src = dt_w + (size_t)layer * 2048 * 64;
        dst = dt_bf + (size_t)layer * 2048 * 64; off = i - N_IN4 - N_XP4;
    } else {
        src = out_w + (size_t)layer * 1024 * 2048;
        dst = out_bf + (size_t)layer * 1024 * 2048; off = i - N_IN4 - N_XP4 - N_DT4;
    }
    const float4* s4 = (const float4*)src + off;
    unsigned int o[8];
#pragma unroll
    for (int j = 0; j < 4; ++j) {
        float4 v = s4[j];
        o[j * 2 + 0] = (unsigned int)f2bf(v.x) | ((unsigned int)f2bf(v.y) << 16);
        o[j * 2 + 1] = (unsigned int)f2bf(v.z) | ((unsigned int)f2bf(v.w) << 16);
    }
    uint4* dp = (uint4*)((unsigned short*)dst + (size_t)off * 4);
    dp[0] = make_uint4(o[0], o[1], o[2], o[3]);
    dp[1] = make_uint4(o[4], o[5], o[6], o[7]);
}

// ---------------- RMSNorm -> bf16 ----------------
__global__ __launch_bounds__(256) void rmsnorm_kernel(const float* __restrict__ x,
                                                      const float* __restrict__ w,
                                                      __hip_bfloat16* __restrict__ out) {
    int row = blockIdx.x;
    const float* xr = x + (size_t)row * D;
    float v[4];
    float s = 0.f;
#pragma unroll
    for (int i = 0; i < 4; ++i) {
        v[i] = xr[threadIdx.x + i * 256];
        s += v[i] * v[i];
    }
#pragma unroll
    for (int off = 32; off > 0; off >>= 1) s += __shfl_xor(s, off, 64);
    __shared__ float red[4];
    int wave = threadIdx.x >> 6;
    if ((threadIdx.x & 63) == 0) red[wave] = s;
    __syncthreads();
    float tot = red[0] + red[1] + red[2] + red[3];
    float inv = rsqrtf(tot * (1.f / D) + 1e-5f);
#pragma unroll
    for (int i = 0; i < 4; ++i) {
        int c = threadIdx.x + i * 256;
        out[(size_t)row * D + c] = __float2bfloat16(v[i] * inv * w[c]);
    }
}

// ---------------- MFMA GEMM, double-buffered, GLD staging ----------------
// C[M,N] = A[M,K]*B[N,K]^T. Tile 128x64x32, 4 waves 2x2.
// ARED=false: A bf16 via GLD. ARED=true: A = sum of KSPLIT fp32 partials (dt_proj; K=64, 2 iters,
//   prologue-bound so the synchronous staging is acceptable there).
// EPI: 0 plain; 1 softplus(c+bias[n])
template <int EPI, bool ARED>
__global__ __launch_bounds__(256, 2) void gemm_mfma(
    const void* __restrict__ Ax, int lda,
    const __hip_bfloat16* __restrict__ Bw, int ldb,
    float* __restrict__ C, int ldc, int Nvalid,
    int kchunk, long zstride,
    const float* __restrict__ bias, long pstride) {
    __shared__ __align__(16) __hip_bfloat16 As[2][128 * BK];
    __shared__ __align__(16) __hip_bfloat16 Bs[2][64 * BK];
    int tid = threadIdx.x;
    int wave = tid >> 6, lane = tid & 63;
    int m0 = blockIdx.y * 128, n0 = blockIdx.x * 64;
    int k_lo = blockIdx.z * kchunk, k_hi = k_lo + kchunk;
    C += (long)blockIdx.z * zstride;
    int wr = wave >> 1, wc = wave & 1;
    int srow = lane >> 2, scol = (lane & 3) * 8;
    int q = lane >> 4, r = lane & 15;

    floatx4 acc[4][2] = {};

    const __hip_bfloat16* gA0b = nullptr;
    const __hip_bfloat16* gA1b = nullptr;
    const float* gA0f = nullptr;
    const float* gA1f = nullptr;
    if (!ARED) {
        gA0b = (const __hip_bfloat16*)Ax + (long)(m0 + wave * 32 + srow) * lda + scol;
        gA1b = gA0b + (long)16 * lda;
    } else {
        gA0f = (const float*)Ax + (long)(m0 + wave * 32 + srow) * lda + scol;
        gA1f = gA0f + (long)16 * lda;
    }
    const __hip_bfloat16* gB = Bw + (long)(n0 + wave * 16 + srow) * ldb + scol;

    auto stage = [&](int k0, int p) {
        if (!ARED) {
#ifdef HAVE_GLD
            GLD(gA0b + k0, &As[p][(wave * 32) * BK]);
            GLD(gA1b + k0, &As[p][(wave * 32 + 16) * BK]);
#else
            *(short8*)(&As[p][(wave * 32) * BK + lane * 8]) = *(const short8*)(gA0b + k0);
            *(short8*)(&As[p][(wave * 32 + 16) * BK + lane * 8]) = *(const short8*)(gA1b + k0);
#endif
        } else {
            floatx4 v0 = {0.f, 0.f, 0.f, 0.f}, v1 = v0, w0 = v0, w1 = v0;
#pragma unroll
            for (int sp = 0; sp < KSPLIT; ++sp) {
                const float* p0 = gA0f + sp * pstride + k0;
                const float* p1 = gA1f + sp * pstride + k0;
                v0 += *(const floatx4*)(p0);
                v1 += *(const floatx4*)(p0 + 4);
                w0 += *(const floatx4*)(p1);
                w1 += *(const floatx4*)(p1 + 4);
            }
            *(short8*)(&As[p][(wave * 32 + srow) * BK + scol]) = pack8(v0, v1);
            *(short8*)(&As[p][(wave * 32 + 16 + srow) * BK + scol]) = pack8(w0, w1);
        }
#ifdef HAVE_GLD
        GLD(gB + k0, &Bs[p][(wave * 16) * BK]);
#else
        *(short8*)(&Bs[p][(wave * 16) * BK + lane * 8]) = *(const short8*)(gB + k0);
#endif
    };

    stage(k_lo, 0);
    int p = 0;
    for (int k0 = k_lo; k0 < k_hi; k0 += BK) {
        __syncthreads();
        if (k0 + BK < k_hi) stage(k0 + BK, p ^ 1);
        const short* Ap = (const short*)As[p];
        const short* Bp = (const short*)Bs[p];
        short8 af[4], bfr[2];
#pragma unroll
        for (int i = 0; i < 4; ++i)
            af[i] = *(const short8*)(Ap + (wr * 64 + i * 16 + r) * BK + q * 8);
#pragma unroll
        for (int j = 0; j < 2; ++j)
            bfr[j] = *(const short8*)(Bp + (wc * 32 + j * 16 + r) * BK + q * 8);
#pragma unroll
        for (int i = 0; i < 4; ++i)
#pragma unroll
            for (int j = 0; j < 2; ++j)
                acc[i][j] = __builtin_amdgcn_mfma_f32_16x16x32_bf16(af[i], bfr[j], acc[i][j], 0, 0, 0);
        p ^= 1;
    }

#pragma unroll
    for (int i = 0; i < 4; ++i) {
        int mrow = m0 + wr * 64 + i * 16 + q * 4;
#pragma unroll
        for (int j = 0; j < 2; ++j) {
            int ncol = n0 + wc * 32 + j * 16 + r;
            if (ncol < Nvalid) {
#pragma unroll
                for (int rr = 0; rr < 4; ++rr) {
                    float v = acc[i][j][rr];
                    int m = mrow + rr;
                    if (EPI == 1) {
                        v += bias[ncol];
                        v = v > 20.f ? v : log1pf(__expf(v));
                    }
                    C[(long)m * ldc + ncol] = v;
                }
            }
        }
    }
}

// ---------------- out_proj split-K reduce + residual ----------------
__global__ __launch_bounds__(256) void reduce2_kernel(const float* __restrict__ part2,
                                                      const float* __restrict__ xin,
                                                      float* __restrict__ out) {
    int i = blockIdx.x * 256 + threadIdx.x;  // float4 index, < L*D/4
    float4 a = ((const float4*)part2)[i];
    float4 b = ((const float4*)(part2 + (size_t)L * D))[i];
    float4 c = ((const float4*)xin)[i];
    ((float4*)out)[i] = make_float4(a.x + b.x + c.x, a.y + b.y + c.y,
                                    a.z + b.z + c.z, a.w + b.w + c.w);
}

// ---------------- causal depthwise conv + bias + SiLU -> bf16 ----------------
__global__ __launch_bounds__(256) void conv_silu_kernel(const float* __restrict__ xz,
                                                        const float* __restrict__ cw,
                                                        const float* __restrict__ cb,
                                                        __hip_bfloat16* __restrict__ u) {
    int idx = blockIdx.x * 256 + threadIdx.x;  // t*DI + d
    int d = idx & (DI - 1);
    int t = idx >> 11;
    float acc = cb[d];
#pragma unroll
    for (int k = 0; k < KCONV; ++k) {
        int tk = t - (KCONV - 1) + k;
        if (tk >= 0) acc += xz[(size_t)tk * (2 * DI) + d] * cw[d * KCONV + k];
    }
    u[idx] = __float2bfloat16(siluf(acc));
}

// ---------------- selective scan: phase A (per-chunk aggregates) ----------------
__global__ __launch_bounds__(256) void scanA_kernel(const float* __restrict__ delta,
                                                    const __hip_bfloat16* __restrict__ u,
                                                    const float* __restrict__ part,
                                                    const float* __restrict__ Alog,
                                                    float* __restrict__ Ach,
                                                    float* __restrict__ Bch) {
    int d = blockIdx.x * 256 + threadIdx.x;
    int c = blockIdx.y;
    __shared__ __align__(16) float Bsh[CT * NSTATE];
    int tt0 = threadIdx.x >> 4, c0 = threadIdx.x & 15;
    {
        float s = 0.f;
        size_t base = (size_t)(c * CT + tt0) * XD + DTR + c0;
#pragma unroll
        for (int sp = 0; sp < KSPLIT; ++sp) s += part[(size_t)sp * L * XD + base];
        Bsh[threadIdx.x] = s;
    }
    __syncthreads();

    float aval[NSTATE];
    const float4* Al4 = (const float4*)(Alog + (size_t)d * NSTATE);
#pragma unroll
    for (int n4 = 0; n4 < 4; ++n4) {
        float4 t = Al4[n4];
        aval[n4 * 4 + 0] = -__expf(t.x);
        aval[n4 * 4 + 1] = -__expf(t.y);
        aval[n4 * 4 + 2] = -__expf(t.z);
        aval[n4 * 4 + 3] = -__expf(t.w);
    }
    float h[NSTATE], ap[NSTATE];
#pragma unroll
    for (int n = 0; n < NSTATE; ++n) { h[n] = 0.f; ap[n] = 1.f; }

    for (int tt = 0; tt < CT; ++tt) {
        int t = c * CT + tt;
        float dl = delta[(size_t)t * DI + d];
        float uu = __bfloat162float(u[(size_t)t * DI + d]);
        float du = dl * uu;
        const float4* Bv = (const float4*)(Bsh + tt * NSTATE);
#pragma unroll
        for (int n4 = 0; n4 < 4; ++n4) {
            float4 b = Bv[n4];
            float bb[4] = {b.x, b.y, b.z, b.w};
#pragma unroll
            for (int k = 0; k < 4; ++k) {
                int n = n4 * 4 + k;
                float a = __expf(dl * aval[n]);
                h[n] = a * h[n] + du * bb[k];
                ap[n] *= a;
            }
        }
    }
    float4* Ao = (float4*)(Ach + ((size_t)c * DI + d) * NSTATE);
    float4* Bo = (float4*)(Bch + ((size_t)c * DI + d) * NSTATE);
#pragma unroll
    for (int n4 = 0; n4 < 4; ++n4) {
        Ao[n4] = make_float4(ap[n4 * 4], ap[n4 * 4 + 1], ap[n4 * 4 + 2], ap[n4 * 4 + 3]);
        Bo[n4] = make_float4(h[n4 * 4], h[n4 * 4 + 1], h[n4 * 4 + 2], h[n4 * 4 + 3]);
    }
}

// ---------------- scan phase B: sequential chunk combine; Hinit overwrites Ach ----------------
__global__ __launch_bounds__(256) void scanB_kernel(float* __restrict__ Ach,
                                                    const float* __restrict__ Bch) {
    long i = blockIdx.x * 256 + threadIdx.x;  // < DI*NSTATE
    const long S = (long)DI * NSTATE;
    float h = 0.f;
    for (int c = 0; c < NC; ++c) {
        float a = Ach[c * S + i];
        float b = Bch[c * S + i];
        Ach[c * S + i] = h;  // becomes Hinit
        h = a * h + b;
    }
}

// ---------------- scan phase C: replay with init state, fused gate -> yg bf16 ----------------
__global__ __launch_bounds__(256) void scanC_kernel(const float* __restrict__ delta,
                                                    const __hip_bfloat16* __restrict__ u,
                                                    const float* __restrict__ part,
                                                    const float* __restrict__ Alog,
                                                    const float* __restrict__ Hin,
                                                    const float* __restrict__ xz,
                                                    const float* __restrict__ Dskip,
                                                    __hip_bfloat16* __restrict__ yg) {
    int d = blockIdx.x * 256 + threadIdx.x;
    int c = blockIdx.y;
    __shared__ __align__(16) float Bsh[CT * NSTATE];
    __shared__ __align__(16) float Csh[CT * NSTATE];
    int tt0 = threadIdx.x >> 4, c0 = threadIdx.x & 15;
    {
        float sb = 0.f, sc = 0.f;
        size_t base = (size_t)(c * CT + tt0) * XD + DTR + c0;
#pragma unroll
        for (int sp = 0; sp < KSPLIT; ++sp) {
            sb += part[(size_t)sp * L * XD + base];
            sc += part[(size_t)sp * L * XD + base + NSTATE];
        }
        Bsh[threadIdx.x] = sb;
        Csh[threadIdx.x] = sc;
    }
    __syncthreads();

    float aval[NSTATE];
    const float4* Al4 = (const float4*)(Alog + (size_t)d * NSTATE);
#pragma unroll
    for (int n4 = 0; n4 < 4; ++n4) {
        float4 t = Al4[n4];
        aval[n4 * 4 + 0] = -__expf(t.x);
        aval[n4 * 4 + 1] = -__expf(t.y);
        aval[n4 * 4 + 2] = -__expf(t.z);
        aval[n4 * 4 + 3] = -__expf(t.w);
    }
    float h[NSTATE];
    const float4* Hi = (const float4*)(Hin + ((size_t)c * DI + d) * NSTATE);
#pragma unroll
    for (int n4 = 0; n4 < 4; ++n4) {
        float4 t = Hi[n4];
        h[n4 * 4 + 0] = t.x; h[n4 * 4 + 1] = t.y; h[n4 * 4 + 2] = t.z; h[n4 * 4 + 3] = t.w;
    }
    float dsk = Dskip[d];

    for (int tt = 0; tt < CT; ++tt) {
        int t = c * CT + tt;
        float dl = delta[(size_t)t * DI + d];
        float uu = __bfloat162float(u[(size_t)t * DI + d]);
        float du = dl * uu;
        const float4* Bv = (const float4*)(Bsh + tt * NSTATE);
        const float4* Cv = (const float4*)(Csh + tt * NSTATE);
        float y = 0.f;
#pragma unroll
        for (int n4 = 0; n4 < 4; ++n4) {
            float4 b = Bv[n4];
            float4 cc = Cv[n4];
            float bb[4] = {b.x, b.y, b.z, b.w};
            float cv[4] = {cc.x, cc.y, cc.z, cc.w};
#pragma unroll
            for (int k = 0; k < 4; ++k) {
                int n = n4 * 4 + k;
                float a = __expf(dl * aval[n]);
                h[n] = a * h[n] + du * bb[k];
                y += h[n] * cv[k];
            }
        }
        float z = xz[(size_t)t * (2 * DI) + DI + d];
        yg[(size_t)t * DI + d] = __float2bfloat16((y + uu * dsk) * siluf(z));
    }
}

// ---------------- host orchestration ----------------
extern "C" void kernel_launch(void* const* d_in, const int* in_sizes, int n_in,
                              void* d_out, int out_size, void* d_ws, size_t ws_size,
                              hipStream_t stream) {
    const float* x      = (const float*)d_in[0];
    const float* norm_w = (const float*)d_in[1];
    const float* in_w   = (const float*)d_in[2];
    const float* conv_w = (const float*)d_in[3];
    const float* conv_b = (const float*)d_in[4];
    const float* xproj_w= (const float*)d_in[5];
    const float* dt_w   = (const float*)d_in[6];
    const float* dt_b   = (const float*)d_in[7];
    const float* A_log  = (const float*)d_in[8];
    const float* D_skip = (const float*)d_in[9];
    const float* out_w  = (const float*)d_in[10];
    float* out = (float*)d_out;

    uint8_t* wp = (uint8_t*)d_ws;
    auto alloc = [&](size_t bytes) {
        uint8_t* p = wp;
        wp += (bytes + 255) & ~(size_t)255;
        return p;
    };
    __hip_bfloat16* w_in_bf  = (__hip_bfloat16*)alloc((size_t)NLAYER * 4096 * 1024 * 2);
    __hip_bfloat16* w_xp_bf  = (__hip_bfloat16*)alloc((size_t)NLAYER * 128 * 2048 * 2);
    __hip_bfloat16* w_dt_bf  = (__hip_bfloat16*)alloc((size_t)NLAYER * 2048 * 64 * 2);
    __hip_bfloat16* w_out_bf = (__hip_bfloat16*)alloc((size_t)NLAYER * 1024 * 2048 * 2);
    __hip_bfloat16* xn_bf    = (__hip_bfloat16*)alloc((size_t)L * D * 2);
    float*          xz       = (float*)alloc((size_t)L * 2 * DI * 4);
    __hip_bfloat16* u_bf     = (__hip_bfloat16*)alloc((size_t)L * DI * 2);
    float*          part     = (float*)alloc((size_t)KSPLIT * L * XD * 4);
    float*          delta    = (float*)alloc((size_t)L * DI * 4);
    __hip_bfloat16* yg_bf    = (__hip_bfloat16*)alloc((size_t)L * DI * 2);
    float*          part2    = (float*)alloc((size_t)2 * L * D * 4);
    float*          Ach      = (float*)alloc((size_t)NC * DI * NSTATE * 4);  // Hinit aliases this
    float*          Bch      = (float*)alloc((size_t)NC * DI * NSTATE * 4);

    cvt_all_kernel<<<(CVT_THREADS + 255) / 256, 256, 0, stream>>>(
        in_w, xproj_w, dt_w, out_w, w_in_bf, w_xp_bf, w_dt_bf, w_out_bf);

    for (int l = 0; l < NLAYER; ++l) {
        const float* xin = (l == 0) ? x : out;
        const __hip_bfloat16* wi = w_in_bf + (size_t)l * 4096 * 1024;
        const __hip_bfloat16* wx = w_xp_bf + (size_t)l * 128 * 2048;
        const __hip_bfloat16* wd = w_dt_bf + (size_t)l * 2048 * 64;
        const __hip_bfloat16* wo = w_out_bf + (size_t)l * 1024 * 2048;

        rmsnorm_kernel<<<L, 256, 0, stream>>>(xin, norm_w + (size_t)l * D, xn_bf);

        // in_proj: [1024,1024]x[4096,1024]^T -> xz
        gemm_mfma<0, false><<<dim3(4096 / 64, L / 128, 1), 256, 0, stream>>>(
            xn_bf, D, wi, D, xz, 4096, 4096, D, 0, nullptr, 0);

        conv_silu_kernel<<<L * DI / 256, 256, 0, stream>>>(
            xz, conv_w + (size_t)l * DI * KCONV, conv_b + (size_t)l * DI, u_bf);

        // x_proj split-K: [1024,2048]x[96(pad128),2048]^T -> part[s][1024][96]
        gemm_mfma<0, false><<<dim3(2, L / 128, KSPLIT), 256, 0, stream>>>(
            u_bf, DI, wx, DI, part, XD, XD, DI / KSPLIT, (long)L * XD, nullptr, 0);

        // dt_proj (A = sum of fp32 partials, fused): [1024,64]x[2048,64]^T -> delta, softplus
        gemm_mfma<1, true><<<dim3(2048 / 64, L / 128, 1), 256, 0, stream>>>(
            part, XD, wd, DTR, delta, DI, DI, DTR, 0,
            dt_b + (size_t)l * DI, (long)L * XD);

        scanA_kernel<<<dim3(DI / 256, NC), 256, 0, stream>>>(
            delta, u_bf, part, A_log + (size_t)l * DI * NSTATE, Ach, Bch);
        scanB_kernel<<<(DI * NSTATE) / 256, 256, 0, stream>>>(Ach, Bch);
        scanC_kernel<<<dim3(DI / 256, NC), 256, 0, stream>>>(
            delta, u_bf, part, A_log + (size_t)l * DI * NSTATE, Ach, xz,
            D_skip + (size_t)l * DI, yg_bf);

        // out_proj split-K=2: [1024,2048]x[1024,2048]^T -> part2[z][1024][1024]
        gemm_mfma<0, false><<<dim3(1024 / 64, L / 128, 2), 256, 0, stream>>>(
            yg_bf, DI, wo, DI, part2, D, D, DI / 2, (long)L * D, nullptr, 0);
        reduce2_kernel<<<(L * D / 4) / 256, 256, 0, stream>>>(part2, xin, out);
    }
}

// Round 7
// 601.642 us; speedup vs baseline: 1.4233x; 1.0606x over previous
//
#include <hip/hip_runtime.h>
#include <hip/hip_bf16.h>
#include <stdint.h>

#define L 1024
#define D 1024
#define NLAYER 4
#define NSTATE 16
#define DI 2048
#define DTR 64
#define KCONV 4
#define XD 96      // DTR + 2*NSTATE
#define NC 64      // scan chunks
#define CT 16      // timesteps per chunk (L/NC)
#define KSPLIT 8   // x_proj split-K
#define BK 32
#define DIST 4     // GEMM prefetch depth (iterations)

typedef __attribute__((ext_vector_type(8))) short short8;
typedef __attribute__((ext_vector_type(4))) float floatx4;

__device__ __forceinline__ float siluf(float x) { return x / (1.f + __expf(-x)); }

__device__ __forceinline__ unsigned short f2bf(float x) {
    __hip_bfloat16 b = __float2bfloat16(x);
    return *reinterpret_cast<unsigned short*>(&b);
}

__device__ __forceinline__ short8 pack8(floatx4 a, floatx4 b) {
    short8 o;
    o[0] = (short)f2bf(a.x); o[1] = (short)f2bf(a.y);
    o[2] = (short)f2bf(a.z); o[3] = (short)f2bf(a.w);
    o[4] = (short)f2bf(b.x); o[5] = (short)f2bf(b.y);
    o[6] = (short)f2bf(b.z); o[7] = (short)f2bf(b.w);
    return o;
}

// Barrier that does NOT drain vmcnt: deep global-load prefetches stay in flight.
// lgkmcnt(0) makes this iteration's ds_writes visible; memory clobber pins IR order.
#define BARRIER_NODRAIN() asm volatile("s_waitcnt lgkmcnt(0)\n\ts_barrier" ::: "memory")

// ---------------- RMSNorm -> bf16 (layer 0 only) ----------------
__global__ __launch_bounds__(256) void rmsnorm_kernel(const float* __restrict__ x,
                                                      const float* __restrict__ w,
                                                      __hip_bfloat16* __restrict__ out) {
    int row = blockIdx.x;
    const float* xr = x + (size_t)row * D;
    float v[4];
    float s = 0.f;
#pragma unroll
    for (int i = 0; i < 4; ++i) {
        v[i] = xr[threadIdx.x + i * 256];
        s += v[i] * v[i];
    }
#pragma unroll
    for (int off = 32; off > 0; off >>= 1) s += __shfl_xor(s, off, 64);
    __shared__ float red[4];
    int wave = threadIdx.x >> 6;
    if ((threadIdx.x & 63) == 0) red[wave] = s;
    __syncthreads();
    float tot = red[0] + red[1] + red[2] + red[3];
    float inv = rsqrtf(tot * (1.f / D) + 1e-5f);
#pragma unroll
    for (int i = 0; i < 4; ++i) {
        int c = threadIdx.x + i * 256;
        out[(size_t)row * D + c] = __float2bfloat16(v[i] * inv * w[c]);
    }
}

// ---------------- pipelined MFMA GEMM: C[M,N] = A[M,K] * B[N,K]^T ----------------
// A bf16, B fp32 (converted to bf16 during latency-hidden ds_write staging).
// Tile 128x64x32, 4 waves 2x2. Register prefetch queue of DIST iterations; raw
// lgkm-only barrier keeps up to 4*DIST global loads in flight across iterations.
// EPI: 0 plain; 1 softplus(c + bias[n]).
template <int EPI, int ITERS>
__global__ __launch_bounds__(256, 2) void gemm_pipe(
    const __hip_bfloat16* __restrict__ A, int lda,
    const float* __restrict__ Bw, int ldb, int Brows,
    float* __restrict__ C, int ldc, int Nvalid,
    long zstride, const float* __restrict__ bias) {
    __shared__ __align__(16) __hip_bfloat16 As[2][128 * BK];
    __shared__ __align__(16) __hip_bfloat16 Bs[2][64 * BK];
    int tid = threadIdx.x;
    int wave = tid >> 6, lane = tid & 63;
    int m0 = blockIdx.y * 128, n0 = blockIdx.x * 64;
    int k_base = blockIdx.z * (ITERS * BK);
    C += (long)blockIdx.z * zstride;
    int wr = wave >> 1, wc = wave & 1;
    int srow = lane >> 2, scol = (lane & 3) * 8;
    int q = lane >> 4, r = lane & 15;

    floatx4 acc[4][2] = {};

    const __hip_bfloat16* gA0 = A + (long)(m0 + wave * 32 + srow) * lda + scol + k_base;
    const __hip_bfloat16* gA1 = gA0 + (long)16 * lda;
    int bn = n0 + wave * 16 + srow;
    const float* gB = Bw + (long)bn * ldb + scol + k_base;
    bool bok = bn < Brows;

    short8 qa0[DIST], qa1[DIST];
    floatx4 qb0[DIST] = {}, qb1[DIST] = {};

    auto ld = [&](int j) {
        int k0 = j * BK;
        int s = j & (DIST - 1);
        qa0[s] = *(const short8*)(gA0 + k0);
        qa1[s] = *(const short8*)(gA1 + k0);
        if (bok) {
            qb0[s] = *(const floatx4*)(gB + k0);
            qb1[s] = *(const floatx4*)(gB + k0 + 4);
        }
    };
    auto wrstage = [&](int j) {
        int p = j & 1, s = j & (DIST - 1);
        *(short8*)(&As[p][(wave * 32 + srow) * BK + scol]) = qa0[s];
        *(short8*)(&As[p][(wave * 32 + 16 + srow) * BK + scol]) = qa1[s];
        *(short8*)(&Bs[p][(wave * 16 + srow) * BK + scol]) = pack8(qb0[s], qb1[s]);
    };

#pragma unroll
    for (int j = 0; j < DIST; ++j)
        if (j < ITERS) ld(j);
    wrstage(0);

#pragma unroll
    for (int k = 0; k < ITERS; ++k) {
        BARRIER_NODRAIN();
        if (k + DIST < ITERS) ld(k + DIST);
        if (k + 1 < ITERS) wrstage(k + 1);
        const short* Ap = (const short*)As[k & 1];
        const short* Bp = (const short*)Bs[k & 1];
        short8 af[4], bfr[2];
#pragma unroll
        for (int i = 0; i < 4; ++i)
            af[i] = *(const short8*)(Ap + (wr * 64 + i * 16 + r) * BK + q * 8);
#pragma unroll
        for (int j = 0; j < 2; ++j)
            bfr[j] = *(const short8*)(Bp + (wc * 32 + j * 16 + r) * BK + q * 8);
#pragma unroll
        for (int i = 0; i < 4; ++i)
#pragma unroll
            for (int j = 0; j < 2; ++j)
                acc[i][j] = __builtin_amdgcn_mfma_f32_16x16x32_bf16(af[i], bfr[j], acc[i][j], 0, 0, 0);
    }

#pragma unroll
    for (int i = 0; i < 4; ++i) {
        int mrow = m0 + wr * 64 + i * 16 + q * 4;
#pragma unroll
        for (int j = 0; j < 2; ++j) {
            int ncol = n0 + wc * 32 + j * 16 + r;
            if (ncol < Nvalid) {
#pragma unroll
                for (int rr = 0; rr < 4; ++rr) {
                    float v = acc[i][j][rr];
                    int m = mrow + rr;
                    if (EPI == 1) {
                        v += bias[ncol];
                        v = v > 20.f ? v : log1pf(__expf(v));
                    }
                    C[(long)m * ldc + ncol] = v;
                }
            }
        }
    }
}

// ---------------- out_proj split-K reduce + residual (+fused RMSNorm for next layer) ----------------
template <bool NORM>
__global__ __launch_bounds__(256) void reduce2_kernel(const float* __restrict__ part2,
                                                      const float* __restrict__ xin,
                                                      const float* __restrict__ nw,
                                                      float* __restrict__ out,
                                                      __hip_bfloat16* __restrict__ xn) {
    int row = blockIdx.x;
    const float* p0 = part2 + (size_t)row * D;
    const float* p1 = p0 + (size_t)L * D;
    const float* xr = xin + (size_t)row * D;
    float v[4];
    float ss = 0.f;
#pragma unroll
    for (int i = 0; i < 4; ++i) {
        int c = threadIdx.x + i * 256;
        v[i] = p0[c] + p1[c] + xr[c];
        out[(size_t)row * D + c] = v[i];
        ss += v[i] * v[i];
    }
    if (NORM) {
#pragma unroll
        for (int off = 32; off > 0; off >>= 1) ss += __shfl_xor(ss, off, 64);
        __shared__ float red[4];
        int wave = threadIdx.x >> 6;
        if ((threadIdx.x & 63) == 0) red[wave] = ss;
        __syncthreads();
        float inv = rsqrtf((red[0] + red[1] + red[2] + red[3]) * (1.f / D) + 1e-5f);
#pragma unroll
        for (int i = 0; i < 4; ++i) {
            int c = threadIdx.x + i * 256;
            xn[(size_t)row * D + c] = __float2bfloat16(v[i] * inv * nw[c]);
        }
    }
}

// ---------------- causal depthwise conv + bias + SiLU -> bf16 ----------------
__global__ __launch_bounds__(256) void conv_silu_kernel(const float* __restrict__ xz,
                                                        const float* __restrict__ cw,
                                                        const float* __restrict__ cb,
                                                        __hip_bfloat16* __restrict__ u) {
    int idx = blockIdx.x * 256 + threadIdx.x;  // t*DI + d
    int d = idx & (DI - 1);
    int t = idx >> 11;
    float acc = cb[d];
#pragma unroll
    for (int k = 0; k < KCONV; ++k) {
        int tk = t - (KCONV - 1) + k;
        if (tk >= 0) acc += xz[(size_t)tk * (2 * DI) + d] * cw[d * KCONV + k];
    }
    u[idx] = __float2bfloat16(siluf(acc));
}

// ---------------- x_proj partial reduce: part[8][L][96] -> xdbl_bf[L][64] + xdblBC[L][32] ----------------
__global__ __launch_bounds__(256) void xred_kernel(const float* __restrict__ part,
                                                   __hip_bfloat16* __restrict__ xdbl_bf,
                                                   float* __restrict__ xdblBC) {
    int i = blockIdx.x * 256 + threadIdx.x;  // < L*96
    int t = i / XD, col = i - t * XD;
    float s = 0.f;
#pragma unroll
    for (int sp = 0; sp < KSPLIT; ++sp) s += part[(size_t)sp * L * XD + i];
    if (col < DTR) xdbl_bf[(size_t)t * DTR + col] = __float2bfloat16(s);
    else xdblBC[(size_t)t * 32 + (col - DTR)] = s;
}

// ---------------- selective scan: phase A (per-chunk aggregates) ----------------
__global__ __launch_bounds__(256) void scanA_kernel(const float* __restrict__ delta,
                                                    const __hip_bfloat16* __restrict__ u,
                                                    const float* __restrict__ xdblBC,
                                                    const float* __restrict__ Alog,
                                                    float* __restrict__ Ach,
                                                    float* __restrict__ Bch) {
    int d = blockIdx.x * 256 + threadIdx.x;
    int c = blockIdx.y;
    __shared__ __align__(16) float Bsh[CT * NSTATE];
    int tt0 = threadIdx.x >> 4, c0 = threadIdx.x & 15;
    Bsh[threadIdx.x] = xdblBC[(size_t)(c * CT + tt0) * 32 + c0];
    __syncthreads();

    float aval[NSTATE];
    const float4* Al4 = (const float4*)(Alog + (size_t)d * NSTATE);
#pragma unroll
    for (int n4 = 0; n4 < 4; ++n4) {
        float4 t = Al4[n4];
        aval[n4 * 4 + 0] = -__expf(t.x);
        aval[n4 * 4 + 1] = -__expf(t.y);
        aval[n4 * 4 + 2] = -__expf(t.z);
        aval[n4 * 4 + 3] = -__expf(t.w);
    }
    float h[NSTATE], ap[NSTATE];
#pragma unroll
    for (int n = 0; n < NSTATE; ++n) { h[n] = 0.f; ap[n] = 1.f; }

    for (int tt = 0; tt < CT; ++tt) {
        int t = c * CT + tt;
        float dl = delta[(size_t)t * DI + d];
        float uu = __bfloat162float(u[(size_t)t * DI + d]);
        float du = dl * uu;
        const float4* Bv = (const float4*)(Bsh + tt * NSTATE);
#pragma unroll
        for (int n4 = 0; n4 < 4; ++n4) {
            float4 b = Bv[n4];
            float bb[4] = {b.x, b.y, b.z, b.w};
#pragma unroll
            for (int k = 0; k < 4; ++k) {
                int n = n4 * 4 + k;
                float a = __expf(dl * aval[n]);
                h[n] = a * h[n] + du * bb[k];
                ap[n] *= a;
            }
        }
    }
    float4* Ao = (float4*)(Ach + ((size_t)c * DI + d) * NSTATE);
    float4* Bo = (float4*)(Bch + ((size_t)c * DI + d) * NSTATE);
#pragma unroll
    for (int n4 = 0; n4 < 4; ++n4) {
        Ao[n4] = make_float4(ap[n4 * 4], ap[n4 * 4 + 1], ap[n4 * 4 + 2], ap[n4 * 4 + 3]);
        Bo[n4] = make_float4(h[n4 * 4], h[n4 * 4 + 1], h[n4 * 4 + 2], h[n4 * 4 + 3]);
    }
}

// ---------------- scan phase B: sequential chunk combine; Hinit overwrites Ach ----------------
__global__ __launch_bounds__(256) void scanB_kernel(float* __restrict__ Ach,
                                                    const float* __restrict__ Bch) {
    long i = blockIdx.x * 256 + threadIdx.x;  // < DI*NSTATE
    const long S = (long)DI * NSTATE;
    float h = 0.f;
    for (int c = 0; c < NC; ++c) {
        float a = Ach[c * S + i];
        float b = Bch[c * S + i];
        Ach[c * S + i] = h;  // becomes Hinit
        h = a * h + b;
    }
}

// ---------------- scan phase C: replay with init state, fused gate -> yg bf16 ----------------
__global__ __launch_bounds__(256) void scanC_kernel(const float* __restrict__ delta,
                                                    const __hip_bfloat16* __restrict__ u,
                                                    const float* __restrict__ xdblBC,
                                                    const float* __restrict__ Alog,
                                                    const float* __restrict__ Hin,
                                                    const float* __restrict__ xz,
                                                    const float* __restrict__ Dskip,
                                                    __hip_bfloat16* __restrict__ yg) {
    int d = blockIdx.x * 256 + threadIdx.x;
    int c = blockIdx.y;
    __shared__ __align__(16) float Bsh[CT * NSTATE];
    __shared__ __align__(16) float Csh[CT * NSTATE];
    int tt0 = threadIdx.x >> 4, c0 = threadIdx.x & 15;
    Bsh[threadIdx.x] = xdblBC[(size_t)(c * CT + tt0) * 32 + c0];
    Csh[threadIdx.x] = xdblBC[(size_t)(c * CT + tt0) * 32 + 16 + c0];
    __syncthreads();

    float aval[NSTATE];
    const float4* Al4 = (const float4*)(Alog + (size_t)d * NSTATE);
#pragma unroll
    for (int n4 = 0; n4 < 4; ++n4) {
        float4 t = Al4[n4];
        aval[n4 * 4 + 0] = -__expf(t.x);
        aval[n4 * 4 + 1] = -__expf(t.y);
        aval[n4 * 4 + 2] = -__expf(t.z);
        aval[n4 * 4 + 3] = -__expf(t.w);
    }
    float h[NSTATE];
    const float4* Hi = (const float4*)(Hin + ((size_t)c * DI + d) * NSTATE);
#pragma unroll
    for (int n4 = 0; n4 < 4; ++n4) {
        float4 t = Hi[n4];
        h[n4 * 4 + 0] = t.x; h[n4 * 4 + 1] = t.y; h[n4 * 4 + 2] = t.z; h[n4 * 4 + 3] = t.w;
    }
    float dsk = Dskip[d];

    for (int tt = 0; tt < CT; ++tt) {
        int t = c * CT + tt;
        float dl = delta[(size_t)t * DI + d];
        float uu = __bfloat162float(u[(size_t)t * DI + d]);
        float du = dl * uu;
        const float4* Bv = (const float4*)(Bsh + tt * NSTATE);
        const float4* Cv = (const float4*)(Csh + tt * NSTATE);
        float y = 0.f;
#pragma unroll
        for (int n4 = 0; n4 < 4; ++n4) {
            float4 b = Bv[n4];
            float4 cc = Cv[n4];
            float bb[4] = {b.x, b.y, b.z, b.w};
            float cv[4] = {cc.x, cc.y, cc.z, cc.w};
#pragma unroll
            for (int k = 0; k < 4; ++k) {
                int n = n4 * 4 + k;
                float a = __expf(dl * aval[n]);
                h[n] = a * h[n] + du * bb[k];
                y += h[n] * cv[k];
            }
        }
        float z = xz[(size_t)t * (2 * DI) + DI + d];
        yg[(size_t)t * DI + d] = __float2bfloat16((y + uu * dsk) * siluf(z));
    }
}

// ---------------- host orchestration ----------------
extern "C" void kernel_launch(void* const* d_in, const int* in_sizes, int n_in,
                              void* d_out, int out_size, void* d_ws, size_t ws_size,
                              hipStream_t stream) {
    const float* x      = (const float*)d_in[0];
    const float* norm_w = (const float*)d_in[1];
    const float* in_w   = (const float*)d_in[2];
    const float* conv_w = (const float*)d_in[3];
    const float* conv_b = (const float*)d_in[4];
    const float* xproj_w= (const float*)d_in[5];
    const float* dt_w   = (const float*)d_in[6];
    const float* dt_b   = (const float*)d_in[7];
    const float* A_log  = (const float*)d_in[8];
    const float* D_skip = (const float*)d_in[9];
    const float* out_w  = (const float*)d_in[10];
    float* out = (float*)d_out;

    uint8_t* wp = (uint8_t*)d_ws;
    auto alloc = [&](size_t bytes) {
        uint8_t* p = wp;
        wp += (bytes + 255) & ~(size_t)255;
        return p;
    };
    __hip_bfloat16* xn_bf   = (__hip_bfloat16*)alloc((size_t)L * D * 2);
    float*          xz      = (float*)alloc((size_t)L * 2 * DI * 4);
    __hip_bfloat16* u_bf    = (__hip_bfloat16*)alloc((size_t)L * DI * 2);
    float*          part    = (float*)alloc((size_t)KSPLIT * L * XD * 4);
    __hip_bfloat16* xdbl_bf = (__hip_bfloat16*)alloc((size_t)L * DTR * 2);
    float*          xdblBC  = (float*)alloc((size_t)L * 32 * 4);
    float*          delta   = (float*)alloc((size_t)L * DI * 4);
    __hip_bfloat16* yg_bf   = (__hip_bfloat16*)alloc((size_t)L * DI * 2);
    float*          part2   = (float*)alloc((size_t)2 * L * D * 4);
    float*          Ach     = (float*)alloc((size_t)NC * DI * NSTATE * 4);  // Hinit aliases this
    float*          Bch     = (float*)alloc((size_t)NC * DI * NSTATE * 4);

    rmsnorm_kernel<<<L, 256, 0, stream>>>(x, norm_w, xn_bf);

    for (int l = 0; l < NLAYER; ++l) {
        const float* xin = (l == 0) ? x : out;

        // in_proj: [1024,1024] x [4096,1024]^T -> xz   (K=1024, 32 iters)
        gemm_pipe<0, 32><<<dim3(4096 / 64, L / 128, 1), 256, 0, stream>>>(
            xn_bf, D, in_w + (size_t)l * 4096 * 1024, D, 4096,
            xz, 4096, 4096, 0, nullptr);

        conv_silu_kernel<<<L * DI / 256, 256, 0, stream>>>(
            xz, conv_w + (size_t)l * DI * KCONV, conv_b + (size_t)l * DI, u_bf);

        // x_proj split-K=8: [1024,2048] x [96,2048]^T -> part[s][1024][96]  (8 iters each)
        gemm_pipe<0, 8><<<dim3(2, L / 128, KSPLIT), 256, 0, stream>>>(
            u_bf, DI, xproj_w + (size_t)l * 96 * 2048, DI, 96,
            part, XD, XD, (long)L * XD, nullptr);
        xred_kernel<<<(L * XD) / 256, 256, 0, stream>>>(part, xdbl_bf, xdblBC);

        // dt_proj: [1024,64] x [2048,64]^T -> delta, softplus(+bias)  (2 iters)
        gemm_pipe<1, 2><<<dim3(2048 / 64, L / 128, 1), 256, 0, stream>>>(
            xdbl_bf, DTR, dt_w + (size_t)l * 2048 * 64, DTR, 2048,
            delta, DI, DI, 0, dt_b + (size_t)l * DI);

        scanA_kernel<<<dim3(DI / 256, NC), 256, 0, stream>>>(
            delta, u_bf, xdblBC, A_log + (size_t)l * DI * NSTATE, Ach, Bch);
        scanB_kernel<<<(DI * NSTATE) / 256, 256, 0, stream>>>(Ach, Bch);
        scanC_kernel<<<dim3(DI / 256, NC), 256, 0, stream>>>(
            delta, u_bf, xdblBC, A_log + (size_t)l * DI * NSTATE, Ach, xz,
            D_skip + (size_t)l * DI, yg_bf);

        // out_proj split-K=2: [1024,2048] x [1024,2048]^T -> part2  (32 iters each)
        gemm_pipe<0, 32><<<dim3(1024 / 64, L / 128, 2), 256, 0, stream>>>(
            yg_bf, DI, out_w + (size_t)l * 1024 * 2048, DI, 1024,
            part2, D, D, (long)L * D, nullptr);

        // reduce + residual; layers 0-2 also produce next layer's RMSNorm input
        if (l < NLAYER - 1)
            reduce2_kernel<true><<<L, 256, 0, stream>>>(
                part2, xin, norm_w + (size_t)(l + 1) * D, out, xn_bf);
        else
            reduce2_kernel<false><<<L, 256, 0, stream>>>(
                part2, xin, nullptr, out, nullptr);
    }
}